// Round 7
// baseline (255.721 us; speedup 1.0000x reference)
//
#include <hip/hip_runtime.h>

#define HH 512
#define WW 512
#define NIMG 12
#define RAD 3
#define TW 64
#define TH 16
#define LW (TW + 2*RAD)   // 70
#define LH (TH + 2*RAD)   // 22
#define RPW 4             // output rows per wave (TH / 4 waves)

typedef float v2 __attribute__((ext_vector_type(2)));

// R7: streaming window + retire-early split + per-row sched_barrier(0).
//
// SESSION LEDGER:
//  R1 fuse2 48KB LDS: 256us (occ 18.6, latency-bound).
//  R2 fuse2 + bounds(256,4): 554us. VGPR clamp 64 < ring ~90 -> spill.
//  R3 fuse2 TH=16: 276us. VGPR tier pins 4 waves/SIMD regardless of LDS.
//  R4 unfused + pi-pair ring: 225.5us BEST. pk_fma_f32 is half-rate on
//     gfx950 (fp32 peak has no packed doubling) -> packing removes movs
//     only. ~45% stall at 92 VGPR (4-5 waves/SIMD).
//  R5 streaming + bounds(256,8): 363us. Clamp -> VGPR 32 -> spill again.
//  R6 streaming unclamped: 252us. Natural VGPR floated into the 65-128
//     tier (scheduler hoists next-row ds_reads, inflating live ranges) ->
//     same waves as R4 + streaming's extra LDS-issue work.
//  R7: make the NATURAL allocation fit the 64 tier: (a) retire-early --
//     U/QN/north-pert fold into d2/d45/e45 at row 3 (identical exprs,
//     identical order -> bit-exact), freeing ~8 regs for the south phase;
//     (b) sched_barrier(0) after each window row stops the ds_read
//     hoisting that sank R6. No launch_bounds clamp -> no spill risk.
//     Tripwire: WRITE must stay ~26.9MB; VGPR<=64 else revert to R4.
//
// NUMERICS CONTRACT (harness-validated R1-R6, absmax 9.77e-4 exactly):
//  - im conv = sequential fma, (ky,kx) row-major, one accumulator per
//    direction; bit-exact -> argmin selection stable. Chains:
//      L/R packed: rows 0..6, pairs {w[d],w[d+3]} d=0..3
//      U scalar: rows 0..3 cols 0..6   | D scalar: rows 3..6 cols 0..6
//      NW/NE packed: rows 0..3 pairs   | SW/SE packed: rows 3..6 pairs
//  - pert quadrant trees EXACTLY as R4/R6 (no reassociation -- absmax
//    headroom unknown): qN=(h0+h1)+(h2+h3), qS=(h3+h4)+(h5+h6),
//    e01=(qN+qS-h3)*w28-cP, e45=qN*w16-cP (computed early, same expr),
//    e67=qS*w16-cP, e2=(qN.x+qN.y-cu)*w28-cP, e3 likewise.
__global__ __launch_bounds__(256) void swf_step(
    const float* __restrict__ im_in, const float* __restrict__ pe_in,
    float* __restrict__ im_out, float* __restrict__ pe_out, int storeIm)
{
    __shared__ float sI[LH * LW];
    __shared__ float sP[LH * LW];

    const int tid = threadIdx.x;
    const int tx = tid & 63;
    const int wv = tid >> 6;          // wave id 0..3
    const int x0 = blockIdx.x * TW;
    const int y0 = blockIdx.y * TH;
    const size_t base = (size_t)blockIdx.z * (size_t)(HH * WW);
    const float* imb = im_in + base;
    const float* peb = pe_in + base;

    // Stage raw tile + halo(3) into LDS, zero padding outside the image
    for (int i = tid; i < LH * LW; i += 256) {
        int r = i / LW;
        int c = i - r * LW;
        int gy = y0 - RAD + r;
        int gx = x0 - RAD + c;
        bool ok = ((unsigned)gy < (unsigned)HH) && ((unsigned)gx < (unsigned)WW);
        int gi = gy * WW + gx;
        sI[i] = ok ? imb[gi] : 0.0f;
        sP[i] = ok ? peb[gi] : 0.0f;
    }
    __syncthreads();

    const float w28 = 1.0f / 28.0f;   // fp32-rounded, as in the ref kernels
    const float w16 = 0.0625f;        // exact
    const v2 w28v = {w28, w28};
    const v2 w16v = {w16, w16};

    const int r0 = wv * RPW;
    int ls = r0 * LW + tx;            // flat 32-bit LDS index (row r0, col tx)

    #pragma unroll 1
    for (int jj = 0; jj < RPW; ++jj) {
        // ---- north phase: rows 0..3 ----
        v2 aLR = {0.f, 0.f}, aQN = {0.f, 0.f};
        float U = 0.f;
        v2 qn01, qn23, h3;
        float cu01, cu23, cP, cI;
        // retained through south phase:
        v2 qN, d45, e45;
        float cu, d2;
        // south accumulators (start at row 3)
        v2 aQS = {0.f, 0.f}, qs01, qs23;
        float Dd = 0.f, cd01, cd23;

        #pragma unroll
        for (int w = 0; w < 7; ++w) {
            const int ri = ls + w * LW;
            const float w0 = sI[ri],     w1 = sI[ri + 1], w2 = sI[ri + 2],
                        w3 = sI[ri + 3], w4 = sI[ri + 4], w5 = sI[ri + 5],
                        w6 = sI[ri + 6];
            const v2 p0 = {w0, w3}, p1 = {w1, w4}, p2 = {w2, w5}, p3 = {w3, w6};

            aLR = __builtin_elementwise_fma(p0, w28v, aLR);   // L cols0-3 | R cols3-6
            aLR = __builtin_elementwise_fma(p1, w28v, aLR);
            aLR = __builtin_elementwise_fma(p2, w28v, aLR);
            aLR = __builtin_elementwise_fma(p3, w28v, aLR);
            if (w < 4) {
                U = fmaf(w0, w28, U);  U = fmaf(w1, w28, U);  U = fmaf(w2, w28, U);
                U = fmaf(w3, w28, U);  U = fmaf(w4, w28, U);  U = fmaf(w5, w28, U);
                U = fmaf(w6, w28, U);
                aQN = __builtin_elementwise_fma(p0, w16v, aQN);
                aQN = __builtin_elementwise_fma(p1, w16v, aQN);
                aQN = __builtin_elementwise_fma(p2, w16v, aQN);
                aQN = __builtin_elementwise_fma(p3, w16v, aQN);
            }
            if (w >= 3) {
                Dd = fmaf(w0, w28, Dd); Dd = fmaf(w1, w28, Dd); Dd = fmaf(w2, w28, Dd);
                Dd = fmaf(w3, w28, Dd); Dd = fmaf(w4, w28, Dd); Dd = fmaf(w5, w28, Dd);
                Dd = fmaf(w6, w28, Dd);
                aQS = __builtin_elementwise_fma(p0, w16v, aQS);
                aQS = __builtin_elementwise_fma(p1, w16v, aQS);
                aQS = __builtin_elementwise_fma(p2, w16v, aQS);
                aQS = __builtin_elementwise_fma(p3, w16v, aQS);
            }

            // ---- pert row w: partials, exact pairwise trees ----
            const float b0 = sP[ri],     b1 = sP[ri + 1], b2 = sP[ri + 2],
                        b3 = sP[ri + 3], b4 = sP[ri + 4], b5 = sP[ri + 5],
                        b6 = sP[ri + 6];
            const v2 h = {(b0 + b1) + (b2 + b3), (b3 + b4) + (b5 + b6)};
            const float c = b3;
            if (w == 0) { qn01 = h;              cu01 = c; }
            if (w == 1) { qn01 = qn01 + h;       cu01 = cu01 + c; }
            if (w == 2) { qn23 = h;              cu23 = c; }
            if (w == 3) {
                qn23 = qn23 + h;     cu23 = cu23 + c;
                qN = qn01 + qn23;    cu = cu01 + cu23;
                h3 = h;  cP = c;  cI = w3;
                // ---- retire-early: north results fold NOW (same exprs,
                //      same order as the R4/R6 epilogue -> bit-identical;
                //      frees U, aQN, qn01/23, cu01/23 for the south phase)
                d2  = U - cI;
                d45 = aQN - (v2){cI, cI};
                e45 = qN * w16v - (v2){cP, cP};
                qs01 = h;            cd01 = c;
            }
            if (w == 4) { qs01 = qs01 + h;       cd01 = cd01 + c; }
            if (w == 5) { qs23 = h;              cd23 = c; }
            if (w == 6) { qs23 = qs23 + h;       cd23 = cd23 + c; }

            // Pin the schedule at row granularity: forbids hoisting the
            // next row's ds_reads over this row's chains (the live-range
            // inflation that pushed R6 past the 64-VGPR tier).
            __builtin_amdgcn_sched_barrier(0);
        }

        const v2 qS = qs01 + qs23;
        const float cd = cd01 + cd23;

        // ---- epilogue (expressions identical to R4/R6) ----
        const v2 cI2 = {cI, cI};
        const v2 d01 = aLR - cI2;
        const float d3 = Dd - cI;
        const v2 d67 = aQS - cI2;
        float d[8] = {d01.x, d01.y, d2, d3, d45.x, d45.y, d67.x, d67.y};

        float e[8];
        {
            const v2 cP2 = {cP, cP};
            v2 eLR = (qN + qS - h3) * w28v - cP2;   // (L, R) -- exact R4 tree
            v2 eQS = qS * w16v - cP2;               // (SW, SE)
            e[0] = eLR.x;  e[1] = eLR.y;
            e[2] = (qN.x + qN.y - cu) * w28 - cP;   // U
            e[3] = (qS.x + qS.y - cd) * w28 - cP;   // D
            e[4] = e45.x;  e[5] = e45.y;            // (NW, NE) -- computed @w3
            e[6] = eQS.x;  e[7] = eQS.y;
        }

        // first-index-wins argmin over |d| (jnp.argmin tie-break)
        float bestAbs = fabsf(d[0]);
        float bd = d[0];
        float be = e[0];
        #pragma unroll
        for (int j = 1; j < 8; ++j) {
            float a = fabsf(d[j]);
            bool take = a < bestAbs;
            bestAbs = take ? a : bestAbs;
            bd = take ? d[j] : bd;
            be = take ? e[j] : be;
        }

        // store index recomputed per row: no 64-bit pointers live in-loop
        const size_t gi = base + (size_t)(y0 + r0 + jj) * WW + (x0 + tx);
        if (storeIm) im_out[gi] = cI + bd;   // bit-exact im chain
        pe_out[gi] = cP + be;

        ls += LW;
    }
}

extern "C" void kernel_launch(void* const* d_in, const int* in_sizes, int n_in,
                              void* d_out, int out_size, void* d_ws, size_t ws_size,
                              hipStream_t stream) {
    const float* im0 = (const float*)d_in[0];
    const float* pe0 = (const float*)d_in[1];
    float* out = (float*)d_out;

    const size_t npix = (size_t)NIMG * HH * WW;   // 3,145,728
    float* imA = (float*)d_ws;                    // 12.6 MB
    float* imB = imA + npix;                      // 12.6 MB
    float* peA = imB + npix;                      // 12.6 MB (ws total 37.7 MB)
    float* peB = out;  // d_out doubles as the second pert buffer; parity
                       // lands the final (iter-5) pert write in d_out.

    dim3 grid(WW / TW, HH / TH, NIMG);            // 8 x 32 x 12 = 3072 blocks
    dim3 block(256);

    swf_step<<<grid, block, 0, stream>>>(im0, pe0, imA, peA, 1);  // iter 0
    swf_step<<<grid, block, 0, stream>>>(imA, peA, imB, peB, 1);  // iter 1
    swf_step<<<grid, block, 0, stream>>>(imB, peB, imA, peA, 1);  // iter 2
    swf_step<<<grid, block, 0, stream>>>(imA, peA, imB, peB, 1);  // iter 3
    swf_step<<<grid, block, 0, stream>>>(imB, peB, imA, peA, 1);  // iter 4
    // iter 5: im store is dead (result = filtered pert only) -> skip
    swf_step<<<grid, block, 0, stream>>>(imA, peA, imB, out, 0);  // iter 5
}

// Round 8
// 221.284 us; speedup vs baseline: 1.1556x; 1.1556x over previous
//
#include <hip/hip_runtime.h>

#define HH 512
#define WW 512
#define NIMG 12
#define RAD 3
#define TW 64
#define TH 16
#define LW (TW + 2*RAD)   // 70
#define LH (TH + 2*RAD)   // 22
#define RPW 4             // output rows per wave (TH / 4 waves)

typedef float v2 __attribute__((ext_vector_type(2)));

#define GPTR const __attribute__((address_space(1))) void*
#define LPTR __attribute__((address_space(3))) void*

// R8: R4 main loop VERBATIM (best measured, 225.5us) + direct-to-LDS
// staging for interior blocks via __builtin_amdgcn_global_load_lds.
//
// SESSION LEDGER:
//  R1 fuse2 48KB LDS: 256us (occ 18.6, latency-bound).
//  R2 fuse2 + bounds(256,4): 554us. VGPR clamp 64 < ring ~90 -> spill.
//  R3 fuse2 TH=16: 276us. VGPR tier pins 4 waves/SIMD regardless of LDS.
//  R4 unfused + pi-pair ring: 225.5us BEST. pk_fma_f32 ~half-rate on
//     gfx950; wall = ~20.7us issue + ~17us stall at 4 waves/SIMD.
//  R5 streaming + bounds(256,8): 363us. Clamp -> VGPR 32 -> spill again.
//  R6 streaming unclamped: 252us. Allocator floats >64; re-reading LDS
//     per row costs +12% issue. Ring's register cache earns its VGPRs.
//  R7 streaming + retire-early + sched_barrier: 255.7us. Pinning didn't
//     recover the tier. Occupancy tiers are coarse (waves halve at 64/128,
//     m69); <=64 unreachable for a 7x7-window live set. Structural arc
//     closed: ring at 4 waves/SIMD is the local optimum.
//  R8: attack the last untouched ISSUE block -- staging. Interior blocks
//     (70%) stage rows direct global->LDS (per-lane global src, uniform
//     LDS base + lane*4, m104/m173 pattern): no div/mod, no bounds math,
//     no VGPR round-trip. Edge blocks keep the proven masked path.
//
// NUMERICS CONTRACT (harness-validated R1-R7, absmax 9.77e-4 exactly):
//  - conv = sequential fma over the 7x7 window, (ky,kx) row-major, one
//    accumulator per direction (bit-exact im path vs the fp32 ref replay).
//  - L/R, NW/NE, SW/SE packed as v_pk_fma lanes; each lane's tap sequence
//    identical to the scalar chain. U/D scalar chains, same tap order.
//  - pi[s][d] = {row[tx+d], row[tx+d+3]}: exactly the operand pair of
//    every packed chain -> zero packing movs.
//  - PERT: quadrant decomposition, trees unchanged since prior-session R5.
//  - Staging change affects WHERE bytes come from, not their values:
//    interior blocks never touch padding, so LDS contents are identical.
template <int NR, int LDW, class F>
__device__ __forceinline__ void ring_pass(
    const float* __restrict__ SI, const float* __restrict__ SP,
    int r0, int tx, F emit)
{
    const float w28 = 1.0f / 28.0f;   // fp32-rounded, as in the ref kernels
    const float w16 = 0.0625f;        // exact
    const v2 w28v = {w28, w28};
    const v2 w16v = {w16, w16};

    v2    pi[7][4];   // pi[slot][d] = {row[tx+d], row[tx+d+3]}
    v2    hlr[7];     // pert row partials {hl, hr}
    float cc[7];      // pert center column

    auto rowload = [&](int slot, int m) {
        const float* rI = SI + m * LDW + tx;
        float w0 = rI[0], w1 = rI[1], w2 = rI[2], w3 = rI[3],
              w4 = rI[4], w5 = rI[5], w6 = rI[6];
        pi[slot][0] = (v2){w0, w3};
        pi[slot][1] = (v2){w1, w4};
        pi[slot][2] = (v2){w2, w5};
        pi[slot][3] = (v2){w3, w6};
        const float* rP = SP + m * LDW + tx;
        float b0 = rP[0], b1 = rP[1], b2 = rP[2], b3 = rP[3],
              b4 = rP[4], b5 = rP[5], b6 = rP[6];
        hlr[slot] = (v2){(b0 + b1) + (b2 + b3), (b3 + b4) + (b5 + b6)};
        cc[slot] = b3;
    };

    #pragma unroll
    for (int m = 0; m < 7; ++m)
        rowload(m, r0 + m);

    #pragma unroll
    for (int jj = 0; jj < NR; ++jj) {
        // ---- im: packed L/R, NW/NE, SW/SE + scalar U, D ----
        v2 aLR = {0.f, 0.f}, aQN = {0.f, 0.f}, aQS = {0.f, 0.f};
        #pragma unroll
        for (int dy = 0; dy < 7; ++dy) {
            const int s = (jj + dy) % 7;
            #pragma unroll
            for (int dx = 0; dx < 4; ++dx)   // L: cols 0..3 | R: cols 3..6
                aLR = __builtin_elementwise_fma(pi[s][dx], w28v, aLR);
        }
        float U = 0.f, Dd = 0.f;
        #pragma unroll
        for (int dy = 0; dy < 4; ++dy) {     // U rows 0..3 | D rows 3..6
            const int su = (jj + dy) % 7;
            const int sd = (jj + dy + 3) % 7;
            // cols 0..6 = pi[0].x pi[1].x pi[2].x pi[3].x pi[1].y pi[2].y pi[3].y
            U = fmaf(pi[su][0].x, w28, U);  U = fmaf(pi[su][1].x, w28, U);
            U = fmaf(pi[su][2].x, w28, U);  U = fmaf(pi[su][3].x, w28, U);
            U = fmaf(pi[su][1].y, w28, U);  U = fmaf(pi[su][2].y, w28, U);
            U = fmaf(pi[su][3].y, w28, U);
            Dd = fmaf(pi[sd][0].x, w28, Dd); Dd = fmaf(pi[sd][1].x, w28, Dd);
            Dd = fmaf(pi[sd][2].x, w28, Dd); Dd = fmaf(pi[sd][3].x, w28, Dd);
            Dd = fmaf(pi[sd][1].y, w28, Dd); Dd = fmaf(pi[sd][2].y, w28, Dd);
            Dd = fmaf(pi[sd][3].y, w28, Dd);
            #pragma unroll
            for (int dx = 0; dx < 4; ++dx) { // NW/NE top rows, SW/SE bottom
                aQN = __builtin_elementwise_fma(pi[su][dx], w16v, aQN);
                aQS = __builtin_elementwise_fma(pi[sd][dx], w16v, aQS);
            }
        }

        const float cI = pi[(jj + 3) % 7][3].x;   // center col 3
        const v2 cI2 = {cI, cI};
        const v2 d01 = aLR - cI2;
        const float d2 = U - cI, d3 = Dd - cI;
        const v2 d45 = aQN - cI2;
        const v2 d67 = aQS - cI2;
        float d[8] = {d01.x, d01.y, d2, d3, d45.x, d45.y, d67.x, d67.y};

        // ---- pert: packed quadrant decomposition (values identical R5) ----
        float e[8];
        const int p0 = (jj + 0) % 7, p1 = (jj + 1) % 7, p2 = (jj + 2) % 7,
                  p3 = (jj + 3) % 7, p4 = (jj + 4) % 7, p5 = (jj + 5) % 7,
                  p6 = (jj + 6) % 7;
        const float cP = cc[p3];
        {
            v2 qN = ((hlr[p0] + hlr[p1]) + (hlr[p2] + hlr[p3])); // (qnw,qne)
            v2 qS = ((hlr[p3] + hlr[p4]) + (hlr[p5] + hlr[p6])); // (qsw,qse)
            float cu = ((cc[p0] + cc[p1]) + (cc[p2] + cc[p3]));
            float cd = ((cc[p3] + cc[p4]) + (cc[p5] + cc[p6]));
            const v2 cP2 = {cP, cP};
            v2 eLR = (qN + qS - hlr[p3]) * w28v - cP2;   // (L, R)
            v2 eQN = qN * w16v - cP2;                    // (NW, NE)
            v2 eQS = qS * w16v - cP2;                    // (SW, SE)
            e[0] = eLR.x;  e[1] = eLR.y;
            e[2] = (qN.x + qN.y - cu) * w28 - cP;        // U
            e[3] = (qS.x + qS.y - cd) * w28 - cP;        // D
            e[4] = eQN.x;  e[5] = eQN.y;
            e[6] = eQS.x;  e[7] = eQS.y;
        }

        // first-index-wins argmin over |d| (jnp.argmin tie-break)
        float bestAbs = fabsf(d[0]);
        float bd = d[0];
        float be = e[0];
        #pragma unroll
        for (int j = 1; j < 8; ++j) {
            float a = fabsf(d[j]);
            bool take = a < bestAbs;
            bestAbs = take ? a : bestAbs;
            bd = take ? d[j] : bd;
            be = take ? e[j] : be;
        }

        emit(jj, cI + bd, cP + be);

        if (jj < NR - 1)
            rowload(jj % 7, r0 + jj + 7);
    }
}

__global__ __launch_bounds__(256) void swf_step(
    const float* __restrict__ im_in, const float* __restrict__ pe_in,
    float* __restrict__ im_out, float* __restrict__ pe_out, int storeIm)
{
    __shared__ float sI[LH * LW];
    __shared__ float sP[LH * LW];

    const int tid = threadIdx.x;
    const int tx = tid & 63;
    const int wv = tid >> 6;          // wave id 0..3
    const int x0 = blockIdx.x * TW;
    const int y0 = blockIdx.y * TH;
    const size_t base = (size_t)blockIdx.z * (size_t)(HH * WW);
    const float* imb = im_in + base;
    const float* peb = pe_in + base;

    // Interior tiles: the full halo'd footprint [y0-3,y0+19)x[x0-3,x0+67)
    // is in-bounds -> stage rows direct global->LDS, no masks, no VGPR
    // round-trip. Per row: one 64-lane issue (cols 0..63) + one 6-lane
    // issue (cols 64..69); LDS base wave-uniform, dest = base + lane*4.
    const bool interior = (blockIdx.x >= 1) && (blockIdx.x <= 6) &&
                          (blockIdx.y >= 1) && (blockIdx.y <= 30);
    if (interior) {
        #pragma unroll 1
        for (int r = wv; r < LH; r += 4) {
            const float* gI = imb + (size_t)(y0 - RAD + r) * WW + (x0 - RAD);
            const float* gP = peb + (size_t)(y0 - RAD + r) * WW + (x0 - RAD);
            __builtin_amdgcn_global_load_lds((GPTR)(gI + tx),
                                             (LPTR)(&sI[r * LW]), 4, 0, 0);
            __builtin_amdgcn_global_load_lds((GPTR)(gP + tx),
                                             (LPTR)(&sP[r * LW]), 4, 0, 0);
            if (tx < 6) {
                __builtin_amdgcn_global_load_lds((GPTR)(gI + 64 + tx),
                                                 (LPTR)(&sI[r * LW + 64]), 4, 0, 0);
                __builtin_amdgcn_global_load_lds((GPTR)(gP + 64 + tx),
                                                 (LPTR)(&sP[r * LW + 64]), 4, 0, 0);
            }
        }
    } else {
        // Edge tiles: proven masked path with zero padding outside image.
        for (int i = tid; i < LH * LW; i += 256) {
            int r = i / LW;
            int c = i - r * LW;
            int gy = y0 - RAD + r;
            int gx = x0 - RAD + c;
            bool ok = ((unsigned)gy < (unsigned)HH) && ((unsigned)gx < (unsigned)WW);
            int gi = gy * WW + gx;
            sI[i] = ok ? imb[gi] : 0.0f;
            sP[i] = ok ? peb[gi] : 0.0f;
        }
    }
    __syncthreads();   // compiler emits vmcnt(0)+lgkmcnt(0) drain here

    const int r0 = wv * RPW;          // wave's slab: rows r0 .. r0+RPW+5
    ring_pass<RPW, LW>(&sI[0], &sP[0], r0, tx,
        [&](int jj, float vI, float vP) {
            const size_t gi = base + (size_t)(y0 + r0 + jj) * WW + (x0 + tx);
            if (storeIm) im_out[gi] = vI;
            pe_out[gi] = vP;
        });
}

extern "C" void kernel_launch(void* const* d_in, const int* in_sizes, int n_in,
                              void* d_out, int out_size, void* d_ws, size_t ws_size,
                              hipStream_t stream) {
    const float* im0 = (const float*)d_in[0];
    const float* pe0 = (const float*)d_in[1];
    float* out = (float*)d_out;

    const size_t npix = (size_t)NIMG * HH * WW;   // 3,145,728
    float* imA = (float*)d_ws;                    // 12.6 MB
    float* imB = imA + npix;                      // 12.6 MB
    float* peA = imB + npix;                      // 12.6 MB (ws total 37.7 MB)
    float* peB = out;  // d_out doubles as the second pert buffer; parity
                       // lands the final (iter-5) pert write in d_out.

    dim3 grid(WW / TW, HH / TH, NIMG);            // 8 x 32 x 12 = 3072 blocks
    dim3 block(256);

    swf_step<<<grid, block, 0, stream>>>(im0, pe0, imA, peA, 1);  // iter 0
    swf_step<<<grid, block, 0, stream>>>(imA, peA, imB, peB, 1);  // iter 1
    swf_step<<<grid, block, 0, stream>>>(imB, peB, imA, peA, 1);  // iter 2
    swf_step<<<grid, block, 0, stream>>>(imA, peA, imB, peB, 1);  // iter 3
    swf_step<<<grid, block, 0, stream>>>(imB, peB, imA, peA, 1);  // iter 4
    // iter 5: im store is dead (result = filtered pert only) -> skip
    swf_step<<<grid, block, 0, stream>>>(imA, peA, imB, out, 0);  // iter 5
}

// Round 9
// 206.962 us; speedup vs baseline: 1.2356x; 1.0692x over previous
//
#include <hip/hip_runtime.h>

#define HH 512
#define WW 512
#define NIMG 12
#define RAD 3
#define TW 64
#define TH 32
#define LW (TW + 2*RAD)   // 70
#define LH (TH + 2*RAD)   // 38
#define RPW 8             // output rows per wave (TH / 4 waves)

typedef float v2 __attribute__((ext_vector_type(2)));

#define GPTR const __attribute__((address_space(1))) void*
#define LPTR __attribute__((address_space(3))) void*

// R9: R8 (best, 221.3us) with a taller slab: TH=32 / RPW=8.
//
// SESSION LEDGER:
//  R1 fuse2 48KB LDS: 256us (occ 18.6, latency-bound).
//  R2 fuse2 + bounds(256,4): 554us. VGPR clamp 64 < ring ~90 -> spill.
//  R3 fuse2 TH=16: 276us. VGPR tier pins 4 waves/SIMD regardless of LDS.
//  R4 unfused + pi-pair ring: 225.5us. pk_fma_f32 ~half-rate on gfx950;
//     wall = ~20.7us issue + ~17us stall at 4 waves/SIMD (tier-locked).
//  R5 streaming + bounds(256,8): 363us. Clamp -> VGPR 32 -> spill.
//  R6 streaming unclamped: 252us. Allocator floats >64; +12% issue.
//  R7 streaming + retire-early + sched_barrier: 255.7us. Arc closed.
//  R8 R4 + global_load_lds interior staging: 221.3us BEST.
//  R9: amortize the remaining per-wave/per-block overheads. RPW 4->8:
//     ring-prologue rowloads per output row 2.5 -> 1.75 (-30% of the
//     ds_read stream); staged halo rows/row 1.375 -> 1.19; barriers and
//     block setup halved. Ring state unchanged -> VGPR ~92 (tripwire).
//     Risk: grid 1536 = 1.5 residency rounds (tail at 2 blk/CU).
//
// NUMERICS CONTRACT (harness-validated R1-R8, absmax 9.77e-4 exactly):
//  - conv = sequential fma over the 7x7 window, (ky,kx) row-major, one
//    accumulator per direction (bit-exact im path vs the fp32 ref replay).
//  - L/R, NW/NE, SW/SE packed as v_pk_fma lanes; each lane's tap sequence
//    identical to the scalar chain. U/D scalar chains, same tap order.
//  - pi[s][d] = {row[tx+d], row[tx+d+3]}: exactly the operand pair of
//    every packed chain -> zero packing movs.
//  - PERT: quadrant decomposition, trees unchanged since prior-session R5.
//  - RPW/TH change only the wave->row mapping; every output row still
//    consumes the identical 7-row window in identical order.
template <int NR, int LDW, class F>
__device__ __forceinline__ void ring_pass(
    const float* __restrict__ SI, const float* __restrict__ SP,
    int r0, int tx, F emit)
{
    const float w28 = 1.0f / 28.0f;   // fp32-rounded, as in the ref kernels
    const float w16 = 0.0625f;        // exact
    const v2 w28v = {w28, w28};
    const v2 w16v = {w16, w16};

    v2    pi[7][4];   // pi[slot][d] = {row[tx+d], row[tx+d+3]}
    v2    hlr[7];     // pert row partials {hl, hr}
    float cc[7];      // pert center column

    auto rowload = [&](int slot, int m) {
        const float* rI = SI + m * LDW + tx;
        float w0 = rI[0], w1 = rI[1], w2 = rI[2], w3 = rI[3],
              w4 = rI[4], w5 = rI[5], w6 = rI[6];
        pi[slot][0] = (v2){w0, w3};
        pi[slot][1] = (v2){w1, w4};
        pi[slot][2] = (v2){w2, w5};
        pi[slot][3] = (v2){w3, w6};
        const float* rP = SP + m * LDW + tx;
        float b0 = rP[0], b1 = rP[1], b2 = rP[2], b3 = rP[3],
              b4 = rP[4], b5 = rP[5], b6 = rP[6];
        hlr[slot] = (v2){(b0 + b1) + (b2 + b3), (b3 + b4) + (b5 + b6)};
        cc[slot] = b3;
    };

    #pragma unroll
    for (int m = 0; m < 7; ++m)
        rowload(m, r0 + m);

    #pragma unroll
    for (int jj = 0; jj < NR; ++jj) {
        // ---- im: packed L/R, NW/NE, SW/SE + scalar U, D ----
        v2 aLR = {0.f, 0.f}, aQN = {0.f, 0.f}, aQS = {0.f, 0.f};
        #pragma unroll
        for (int dy = 0; dy < 7; ++dy) {
            const int s = (jj + dy) % 7;
            #pragma unroll
            for (int dx = 0; dx < 4; ++dx)   // L: cols 0..3 | R: cols 3..6
                aLR = __builtin_elementwise_fma(pi[s][dx], w28v, aLR);
        }
        float U = 0.f, Dd = 0.f;
        #pragma unroll
        for (int dy = 0; dy < 4; ++dy) {     // U rows 0..3 | D rows 3..6
            const int su = (jj + dy) % 7;
            const int sd = (jj + dy + 3) % 7;
            // cols 0..6 = pi[0].x pi[1].x pi[2].x pi[3].x pi[1].y pi[2].y pi[3].y
            U = fmaf(pi[su][0].x, w28, U);  U = fmaf(pi[su][1].x, w28, U);
            U = fmaf(pi[su][2].x, w28, U);  U = fmaf(pi[su][3].x, w28, U);
            U = fmaf(pi[su][1].y, w28, U);  U = fmaf(pi[su][2].y, w28, U);
            U = fmaf(pi[su][3].y, w28, U);
            Dd = fmaf(pi[sd][0].x, w28, Dd); Dd = fmaf(pi[sd][1].x, w28, Dd);
            Dd = fmaf(pi[sd][2].x, w28, Dd); Dd = fmaf(pi[sd][3].x, w28, Dd);
            Dd = fmaf(pi[sd][1].y, w28, Dd); Dd = fmaf(pi[sd][2].y, w28, Dd);
            Dd = fmaf(pi[sd][3].y, w28, Dd);
            #pragma unroll
            for (int dx = 0; dx < 4; ++dx) { // NW/NE top rows, SW/SE bottom
                aQN = __builtin_elementwise_fma(pi[su][dx], w16v, aQN);
                aQS = __builtin_elementwise_fma(pi[sd][dx], w16v, aQS);
            }
        }

        const float cI = pi[(jj + 3) % 7][3].x;   // center col 3
        const v2 cI2 = {cI, cI};
        const v2 d01 = aLR - cI2;
        const float d2 = U - cI, d3 = Dd - cI;
        const v2 d45 = aQN - cI2;
        const v2 d67 = aQS - cI2;
        float d[8] = {d01.x, d01.y, d2, d3, d45.x, d45.y, d67.x, d67.y};

        // ---- pert: packed quadrant decomposition (values identical R5) ----
        float e[8];
        const int p0 = (jj + 0) % 7, p1 = (jj + 1) % 7, p2 = (jj + 2) % 7,
                  p3 = (jj + 3) % 7, p4 = (jj + 4) % 7, p5 = (jj + 5) % 7,
                  p6 = (jj + 6) % 7;
        const float cP = cc[p3];
        {
            v2 qN = ((hlr[p0] + hlr[p1]) + (hlr[p2] + hlr[p3])); // (qnw,qne)
            v2 qS = ((hlr[p3] + hlr[p4]) + (hlr[p5] + hlr[p6])); // (qsw,qse)
            float cu = ((cc[p0] + cc[p1]) + (cc[p2] + cc[p3]));
            float cd = ((cc[p3] + cc[p4]) + (cc[p5] + cc[p6]));
            const v2 cP2 = {cP, cP};
            v2 eLR = (qN + qS - hlr[p3]) * w28v - cP2;   // (L, R)
            v2 eQN = qN * w16v - cP2;                    // (NW, NE)
            v2 eQS = qS * w16v - cP2;                    // (SW, SE)
            e[0] = eLR.x;  e[1] = eLR.y;
            e[2] = (qN.x + qN.y - cu) * w28 - cP;        // U
            e[3] = (qS.x + qS.y - cd) * w28 - cP;        // D
            e[4] = eQN.x;  e[5] = eQN.y;
            e[6] = eQS.x;  e[7] = eQS.y;
        }

        // first-index-wins argmin over |d| (jnp.argmin tie-break)
        float bestAbs = fabsf(d[0]);
        float bd = d[0];
        float be = e[0];
        #pragma unroll
        for (int j = 1; j < 8; ++j) {
            float a = fabsf(d[j]);
            bool take = a < bestAbs;
            bestAbs = take ? a : bestAbs;
            bd = take ? d[j] : bd;
            be = take ? e[j] : be;
        }

        emit(jj, cI + bd, cP + be);

        if (jj < NR - 1)
            rowload(jj % 7, r0 + jj + 7);
    }
}

__global__ __launch_bounds__(256) void swf_step(
    const float* __restrict__ im_in, const float* __restrict__ pe_in,
    float* __restrict__ im_out, float* __restrict__ pe_out, int storeIm)
{
    __shared__ float sI[LH * LW];
    __shared__ float sP[LH * LW];

    const int tid = threadIdx.x;
    const int tx = tid & 63;
    const int wv = tid >> 6;          // wave id 0..3
    const int x0 = blockIdx.x * TW;
    const int y0 = blockIdx.y * TH;
    const size_t base = (size_t)blockIdx.z * (size_t)(HH * WW);
    const float* imb = im_in + base;
    const float* peb = pe_in + base;

    // Interior tiles: full halo'd footprint [y0-3,y0+35)x[x0-3,x0+67)
    // in-bounds -> stage rows direct global->LDS (per-lane global src,
    // wave-uniform LDS base + lane*4). Edge tiles: proven masked path.
    const bool interior = (blockIdx.x >= 1) && (blockIdx.x <= 6) &&
                          (blockIdx.y >= 1) && (blockIdx.y <= (HH/TH - 2));
    if (interior) {
        #pragma unroll 1
        for (int r = wv; r < LH; r += 4) {
            const float* gI = imb + (size_t)(y0 - RAD + r) * WW + (x0 - RAD);
            const float* gP = peb + (size_t)(y0 - RAD + r) * WW + (x0 - RAD);
            __builtin_amdgcn_global_load_lds((GPTR)(gI + tx),
                                             (LPTR)(&sI[r * LW]), 4, 0, 0);
            __builtin_amdgcn_global_load_lds((GPTR)(gP + tx),
                                             (LPTR)(&sP[r * LW]), 4, 0, 0);
            if (tx < 6) {
                __builtin_amdgcn_global_load_lds((GPTR)(gI + 64 + tx),
                                                 (LPTR)(&sI[r * LW + 64]), 4, 0, 0);
                __builtin_amdgcn_global_load_lds((GPTR)(gP + 64 + tx),
                                                 (LPTR)(&sP[r * LW + 64]), 4, 0, 0);
            }
        }
    } else {
        for (int i = tid; i < LH * LW; i += 256) {
            int r = i / LW;
            int c = i - r * LW;
            int gy = y0 - RAD + r;
            int gx = x0 - RAD + c;
            bool ok = ((unsigned)gy < (unsigned)HH) && ((unsigned)gx < (unsigned)WW);
            int gi = gy * WW + gx;
            sI[i] = ok ? imb[gi] : 0.0f;
            sP[i] = ok ? peb[gi] : 0.0f;
        }
    }
    __syncthreads();   // compiler emits vmcnt(0)+lgkmcnt(0) drain here

    const int r0 = wv * RPW;          // wave's slab: rows r0 .. r0+RPW+5
    ring_pass<RPW, LW>(&sI[0], &sP[0], r0, tx,
        [&](int jj, float vI, float vP) {
            const size_t gi = base + (size_t)(y0 + r0 + jj) * WW + (x0 + tx);
            if (storeIm) im_out[gi] = vI;
            pe_out[gi] = vP;
        });
}

extern "C" void kernel_launch(void* const* d_in, const int* in_sizes, int n_in,
                              void* d_out, int out_size, void* d_ws, size_t ws_size,
                              hipStream_t stream) {
    const float* im0 = (const float*)d_in[0];
    const float* pe0 = (const float*)d_in[1];
    float* out = (float*)d_out;

    const size_t npix = (size_t)NIMG * HH * WW;   // 3,145,728
    float* imA = (float*)d_ws;                    // 12.6 MB
    float* imB = imA + npix;                      // 12.6 MB
    float* peA = imB + npix;                      // 12.6 MB (ws total 37.7 MB)
    float* peB = out;  // d_out doubles as the second pert buffer; parity
                       // lands the final (iter-5) pert write in d_out.

    dim3 grid(WW / TW, HH / TH, NIMG);            // 8 x 16 x 12 = 1536 blocks
    dim3 block(256);

    swf_step<<<grid, block, 0, stream>>>(im0, pe0, imA, peA, 1);  // iter 0
    swf_step<<<grid, block, 0, stream>>>(imA, peA, imB, peB, 1);  // iter 1
    swf_step<<<grid, block, 0, stream>>>(imB, peB, imA, peA, 1);  // iter 2
    swf_step<<<grid, block, 0, stream>>>(imA, peA, imB, peB, 1);  // iter 3
    swf_step<<<grid, block, 0, stream>>>(imB, peB, imA, peA, 1);  // iter 4
    // iter 5: im store is dead (result = filtered pert only) -> skip
    swf_step<<<grid, block, 0, stream>>>(imA, peA, imB, out, 0);  // iter 5
}